// Round 22
// baseline (257.199 us; speedup 1.0000x reference)
//
#include <hip/hip_runtime.h>
#include <hip/hip_fp16.h>

#define CC 256
#define HWIMG 4096
#define NPIX 131072
#define KCODES 1024
#define FULLCAP 32768
#define FULL2CAP 8192
#define KMARGIN 0.0625f   // fp16 key-space margin <=> distance margin 0.125
#define FM2 0.002f        // fp32 sweep margin (error bound ~1e-4)

typedef _Float16 half8 __attribute__((ext_vector_type(8)));
typedef short short8v __attribute__((ext_vector_type(8)));
typedef float f32x4 __attribute__((ext_vector_type(4)));
typedef unsigned short u16;
typedef unsigned int u32;

__device__ __forceinline__ void gld16(const void* g, void* l) {
    __builtin_amdgcn_global_load_lds(
        (const __attribute__((address_space(1))) void*)g,
        (__attribute__((address_space(3))) void*)l, 16, 0, 0);
}

// min-semantics sorted-triple merge with index tie-breaks
__device__ __forceinline__ void merge3(
    float& m1, int& i1, float& m2, int& i2, float& m3,
    float b1, int j1, float b2, int j2, float b3)
{
    if (b1 < m1 || (b1 == m1 && j1 < i1)) {
        float t; int ti;
        t = m1; m1 = b1; b1 = t;  ti = i1; i1 = j1; j1 = ti;
        t = m2; m2 = b2; b2 = t;  ti = i2; i2 = j2; j2 = ti;
        t = m3; m3 = b3; b3 = t;
    }
    if (b1 < m2 || (b1 == m2 && j1 < i2)) {
        m3 = fminf(m2, b2);
        m2 = b1; i2 = j1;
    } else {
        m3 = fminf(m3, b1);
    }
}

// e image: [tile 32][cpair 4][32 rows][128B]; tile = code>>5, row = code&31;
// 8 slots of 16B; slot = b*4+kg covers ch cpair*64+b*32+kg*8;
// phys slot = slot ^ (row & 7).

// ---------- prep_e: codebook -> fp16 tile-images + (-esq/2) + zero counters --
__global__ __launch_bounds__(256) void prep_e(const float* __restrict__ cb,
    char* __restrict__ e_prep, float* __restrict__ esq, int* __restrict__ cnts)
{
    __shared__ u16 eh[256];
    __shared__ float red[4];
    int k = blockIdx.x, c = threadIdx.x;
    float v = cb[(size_t)k * CC + c];
    eh[c] = __half_as_ushort(__float2half(v));
    float s = v * v;
    #pragma unroll
    for (int m = 32; m; m >>= 1) s += __shfl_xor(s, m, 64);
    if ((c & 63) == 0) red[c >> 6] = s;
    __syncthreads();
    if (c == 0) {
        esq[k] = -0.5f * ((red[0] + red[1]) + (red[2] + red[3]));
        if (k == 0) { cnts[0] = 0; cnts[1] = 0; cnts[2] = 0; }
    }
    if (c < 32) {
        int cpair = c >> 3, phys = c & 7;
        int tile = k >> 5, row = k & 31;
        int slot = phys ^ (row & 7);
        int cst = cpair * 64 + (slot >> 2) * 32 + (slot & 3) * 8;
        short8v w;
        #pragma unroll
        for (int j = 0; j < 8; ++j) w[j] = (short)eh[cst + j];
        *(short8v*)(e_prep + (size_t)tile * 16384 + cpair * 4096 + row * 128 + phys * 16) = w;
    }
}

// ---------- prep_xT: x NCHW fp32 -> fp16 frag-major image (d_out) + xsq ------
__global__ __launch_bounds__(256) void prep_xT(const float* __restrict__ x,
    char* __restrict__ x_frag, float* __restrict__ xsq)
{
    __shared__ u32 pk[64 * 261];
    __shared__ float xsq_p[256];
    const int blk = blockIdx.x, t = threadIdx.x;
    const float* xb = x + (size_t)(blk >> 6) * (CC * HWIMG) + (blk & 63) * 64;
    #pragma unroll 4
    for (int p = 0; p < 16; ++p) {
        int c = p * 16 + (t >> 4);
        int px4 = (t & 15) * 4;
        float4 v = *(const float4*)&xb[(size_t)c * HWIMG + px4];
        float vv[4] = {v.x, v.y, v.z, v.w};
        #pragma unroll
        for (int i = 0; i < 4; ++i)
            pk[(px4 + i) * 261 + c] = (u32)__half_as_ushort(__float2half(vv[i]));
    }
    __syncthreads();
    {
        int px = t & 63, qr = t >> 6;
        const u32* pr = &pk[px * 261 + qr * 64];
        float s = 0.f;
        #pragma unroll 4
        for (int c = 0; c < 64; ++c) {
            float h = __half2float(__ushort_as_half((u16)pr[c]));
            s = fmaf(h, h, s);
        }
        xsq_p[t] = s;
    }
    char* obase = x_frag + (size_t)blk * 32768;
    #pragma unroll
    for (int i = 0; i < 8; ++i) {
        int gid = t + 256 * i;            // [f 4][kc 8][l 64]
        int l = gid & 63;
        int kc = (gid >> 6) & 7, f = gid >> 9;
        int px = f * 16 + (l & 15);
        int c0 = kc * 32 + (l >> 4) * 8;
        const u32* pr = &pk[px * 261 + c0];
        short8v ov;
        #pragma unroll
        for (int j = 0; j < 8; ++j) ov[j] = (short)(pr[j] & 0xFFFF);
        *(short8v*)(obase + gid * 16) = ov;
    }
    __syncthreads();
    if (t < 64)
        xsq[blk * 64 + t] = (xsq_p[t] + xsq_p[t + 64]) + (xsq_p[t + 128] + xsq_p[t + 192]);
}

// ---------- dist: x-stationary MFMA, 32-px waves, acc double-pipeline --------
// Epilogue of tile t-1 (VALU) overlaps tile t's MFMAs (separate pipes).
__global__ __launch_bounds__(256, 4) void dist_kernel(
    const char* __restrict__ x_frag, const char* __restrict__ e_prep,
    const float* __restrict__ esq_g,
    int* __restrict__ min_idx, float* __restrict__ min_d,
    int* __restrict__ cnts, int* __restrict__ full_list)
{
    __shared__ char smem[36864];          // 2 x 16KB e dbuf | 4KB (-esq/2)
    char* esql = smem + 32768;

    const int t = threadIdx.x;
    const int l = t & 63;
    const int wid = t >> 6;
    const int lrow = l & 15;
    const int kg   = l >> 4;
    const int ph0  = ((kg    ) ^ (lrow & 7)) * 16 + lrow * 128;
    const int ph1  = ((kg ^ 4) ^ (lrow & 7)) * 16 + lrow * 128;
    const int pxbase = blockIdx.x * 128 + wid * 32;

    half8 Xreg[2][8];
    #pragma unroll
    for (int f = 0; f < 2; ++f)
        #pragma unroll
        for (int kc = 0; kc < 8; ++kc)
            Xreg[f][kc] = *(const half8*)(x_frag +
                (size_t)(((pxbase >> 4) + f) * 8 + kc) * 1024 + l * 16);
    #pragma unroll
    for (int f = 0; f < 2; ++f)
        #pragma unroll
        for (int kc = 0; kc < 8; ++kc)
            asm volatile("" : "+v"(Xreg[f][kc]));

    gld16(esq_g + wid * 256 + l * 4, esql + wid * 1024);

#define STAGE(cur_, tc_) do {                                                  \
        const char* ee_ = e_prep + (size_t)(tc_) * 16384 + wid * 4096;         \
        char* bb_ = smem + (cur_) * 16384 + wid * 4096;                        \
        _Pragma("unroll")                                                      \
        for (int i_ = 0; i_ < 4; ++i_)                                         \
            gld16(ee_ + i_ * 1024 + l * 16, bb_ + i_ * 1024);                  \
    } while (0)

#define MTILE(ACC_, tc_, cur_) do {                                            \
        const char* eL_ = smem + (cur_) * 16384;                               \
        _Pragma("unroll")                                                      \
        for (int mq_ = 0; mq_ < 2; ++mq_) {                                    \
            float4 e4_ = *(const float4*)(esql + ((tc_) * 32 + mq_ * 16 + kg * 4) * 4); \
            _Pragma("unroll")                                                  \
            for (int f_ = 0; f_ < 2; ++f_)                                     \
                ACC_[mq_][f_] = (f32x4){e4_.x, e4_.y, e4_.z, e4_.w};           \
        }                                                                      \
        _Pragma("unroll")                                                      \
        for (int kc_ = 0; kc_ < 8; ++kc_) {                                    \
            const int po_ = (kc_ >> 1) * 4096 + ((kc_ & 1) ? ph1 : ph0);       \
            half8 A_[2];                                                       \
            _Pragma("unroll")                                                  \
            for (int mq_ = 0; mq_ < 2; ++mq_)                                  \
                A_[mq_] = *(const half8*)(eL_ + po_ + mq_ * 2048);             \
            _Pragma("unroll")                                                  \
            for (int mq_ = 0; mq_ < 2; ++mq_)                                  \
                _Pragma("unroll")                                              \
                for (int f_ = 0; f_ < 2; ++f_)                                 \
                    ACC_[mq_][f_] = __builtin_amdgcn_mfma_f32_16x16x32_f16(    \
                        A_[mq_], Xreg[f_][kc_], ACC_[mq_][f_], 0, 0, 0);       \
        }                                                                      \
    } while (0)

#define EPI(ACC_, tc_) do {                                                    \
        _Pragma("unroll")                                                      \
        for (int mq_ = 0; mq_ < 2; ++mq_) {                                    \
            const int cb0_ = (tc_) * 32 + mq_ * 16 + kg * 4;                   \
            _Pragma("unroll")                                                  \
            for (int f_ = 0; f_ < 2; ++f_) {                                   \
                _Pragma("unroll")                                              \
                for (int q_ = 0; q_ < 4; ++q_) {                               \
                    float a_ = ACC_[mq_][f_][q_];                              \
                    float o1_ = m1s[f_];                                       \
                    m2s[f_] = __builtin_amdgcn_fmed3f(o1_, m2s[f_], a_);       \
                    bool gt_ = a_ > o1_;                                       \
                    m1s[f_] = fmaxf(o1_, a_);                                  \
                    i1s[f_] = gt_ ? (cb0_ + q_) : i1s[f_];                     \
                }                                                              \
            }                                                                  \
        }                                                                      \
    } while (0)

    STAGE(0, 0);
    STAGE(1, 1);

    float m1s[2], m2s[2]; int i1s[2];
    #pragma unroll
    for (int f = 0; f < 2; ++f) { m1s[f] = -3.4e38f; m2s[f] = -3.4e38f; i1s[f] = 0; }

    f32x4 accA[2][2], accB[2][2];

    // tile 0 -> accA (no prior epilogue)
    asm volatile("s_waitcnt vmcnt(4)" ::: "memory");
    __builtin_amdgcn_s_barrier();
    __builtin_amdgcn_sched_barrier(0);
    MTILE(accA, 0, 0);
    __builtin_amdgcn_sched_barrier(0);
    __builtin_amdgcn_s_barrier();
    STAGE(0, 2);

    for (int tp = 0; tp < 15; ++tp) {
        const int t1 = 2 * tp + 1, t2 = 2 * tp + 2;
        asm volatile("s_waitcnt vmcnt(4)" ::: "memory");
        __builtin_amdgcn_s_barrier();
        __builtin_amdgcn_sched_barrier(0);
        MTILE(accB, t1, 1);
        EPI(accA, t1 - 1);
        __builtin_amdgcn_sched_barrier(0);
        __builtin_amdgcn_s_barrier();
        STAGE(1, t1 + 2);
        asm volatile("s_waitcnt vmcnt(4)" ::: "memory");
        __builtin_amdgcn_s_barrier();
        __builtin_amdgcn_sched_barrier(0);
        MTILE(accA, t2, 0);
        EPI(accB, t1);
        __builtin_amdgcn_sched_barrier(0);
        __builtin_amdgcn_s_barrier();
        if (tp < 14) STAGE(0, t2 + 2);
    }
    // tile 31 -> accB
    asm volatile("s_waitcnt vmcnt(0)" ::: "memory");
    __builtin_amdgcn_s_barrier();
    __builtin_amdgcn_sched_barrier(0);
    MTILE(accB, 31, 1);
    EPI(accA, 30);
    EPI(accB, 31);
#undef STAGE
#undef MTILE
#undef EPI

    // final: merge the 4 kg-lanes per pixel (max-key semantics)
    #pragma unroll
    for (int f = 0; f < 2; ++f) {
        float m1 = m1s[f], m2 = m2s[f]; int i1 = i1s[f];
        #pragma unroll
        for (int msk = 16; msk <= 32; msk <<= 1) {
            float o1 = __shfl_xor(m1, msk, 64);
            int   oi = __shfl_xor(i1, msk, 64);
            float o2 = __shfl_xor(m2, msk, 64);
            if (o1 > m1 || (o1 == m1 && oi < i1)) {
                m2 = fmaxf(fmaxf(m2, o2), m1); m1 = o1; i1 = oi;
            } else {
                m2 = fmaxf(fmaxf(m2, o2), o1);
            }
        }
        if (kg == 0) {
            int n = pxbase + f * 16 + lrow;
            min_idx[n] = i1;
            min_d[n] = -2.0f * m1;       // = esq[i1] - 2*dot (for loss)
            if (m1 - m2 <= KMARGIN) {
                int slot = atomicAdd(&cnts[0], 1);
                if (slot < FULLCAP) full_list[slot] = n;
            }
        }
    }
}

// ---------- recheck_sweep8: fp32 sweep, 8 px/block, classify ----------------
__global__ __launch_bounds__(256) void recheck_sweep8(
    const float* __restrict__ x, const float* __restrict__ cb,
    int* __restrict__ cnts, const int* __restrict__ flag_list,
    int* __restrict__ min_idx, float* __restrict__ min_d,
    const float* __restrict__ xsq,
    int2* __restrict__ pair_list, int* __restrict__ full2_list)
{
    __shared__ float xs[8][CC];
    __shared__ float wm1[8][4], wm2[8][4], wm3[8][4];
    __shared__ int   wi1[8][4], wi2[8][4];
    int cnt = cnts[0]; if (cnt > FULLCAP) cnt = FULLCAP;
    int ngrp = (cnt + 7) >> 3;
    const int t = threadIdx.x;
    const int l = t & 63, wid = t >> 6;

    for (int g = blockIdx.x; g < ngrp; g += gridDim.x) {
        int npx = cnt - g * 8; if (npx > 8) npx = 8;
        for (int i = t; i < npx * 256; i += 256) {
            int p = i >> 8, c = i & 255;
            int n = flag_list[g * 8 + p];
            xs[p][c] = x[(size_t)(n >> 12) * CC * HWIMG + (size_t)c * HWIMG + (n & 4095)];
        }
        __syncthreads();

        float s[4][8];
        #pragma unroll
        for (int kk = 0; kk < 4; ++kk)
            #pragma unroll
            for (int p = 0; p < 8; ++p) s[kk][p] = 0.f;
        const float* er = cb + (size_t)t * 4 * CC;
        #pragma unroll 2
        for (int c4 = 0; c4 < 64; ++c4) {
            float4 e0 = *(const float4*)&er[c4 * 4];
            float4 e1 = *(const float4*)&er[CC + c4 * 4];
            float4 e2 = *(const float4*)&er[2 * CC + c4 * 4];
            float4 e3 = *(const float4*)&er[3 * CC + c4 * 4];
            float ea[4][4] = {{e0.x, e0.y, e0.z, e0.w}, {e1.x, e1.y, e1.z, e1.w},
                              {e2.x, e2.y, e2.z, e2.w}, {e3.x, e3.y, e3.z, e3.w}};
            #pragma unroll
            for (int p = 0; p < 8; ++p) {
                float4 xq = *(const float4*)&xs[p][c4 * 4];
                float xa[4] = {xq.x, xq.y, xq.z, xq.w};
                #pragma unroll
                for (int kk = 0; kk < 4; ++kk) {
                    float d0 = xa[0] - ea[kk][0];
                    float d1 = xa[1] - ea[kk][1];
                    float d2 = xa[2] - ea[kk][2];
                    float d3 = xa[3] - ea[kk][3];
                    s[kk][p] = fmaf(d0, d0, fmaf(d1, d1, fmaf(d2, d2, fmaf(d3, d3, s[kk][p]))));
                }
            }
        }

        #pragma unroll
        for (int p = 0; p < 8; ++p) {
            float m1 = 3.4e38f, m2 = 3.4e38f, m3 = 3.4e38f; int i1 = 0, i2 = 0;
            #pragma unroll
            for (int kk = 0; kk < 4; ++kk) {
                float d = s[kk][p]; int idx = t * 4 + kk;
                if (d < m1)      { m3 = m2; m2 = m1; i2 = i1; m1 = d; i1 = idx; }
                else if (d < m2) { m3 = m2; m2 = d; i2 = idx; }
                else if (d < m3) { m3 = d; }
            }
            #pragma unroll
            for (int msk = 1; msk <= 32; msk <<= 1) {
                float b1 = __shfl_xor(m1, msk, 64);
                float b2 = __shfl_xor(m2, msk, 64);
                float b3 = __shfl_xor(m3, msk, 64);
                int  j1 = __shfl_xor(i1, msk, 64);
                int  j2 = __shfl_xor(i2, msk, 64);
                merge3(m1, i1, m2, i2, m3, b1, j1, b2, j2, b3);
            }
            if (l == 0) {
                wm1[p][wid] = m1; wm2[p][wid] = m2; wm3[p][wid] = m3;
                wi1[p][wid] = i1; wi2[p][wid] = i2;
            }
        }
        __syncthreads();
        if (t < npx) {
            float m1 = wm1[t][0], m2 = wm2[t][0], m3 = wm3[t][0];
            int i1 = wi1[t][0], i2 = wi2[t][0];
            #pragma unroll
            for (int w = 1; w < 4; ++w)
                merge3(m1, i1, m2, i2, m3,
                       wm1[t][w], wi1[t][w], wm2[t][w], wi2[t][w], wm3[t][w]);
            int n = flag_list[g * 8 + t];
            if (m3 - m1 <= FM2) {
                int slot = atomicAdd(&cnts[2], 1);
                if (slot < FULL2CAP) full2_list[slot] = n;
            } else if (m2 - m1 <= FM2) {
                int slot = atomicAdd(&cnts[1], 1);
                if (slot < FULLCAP) pair_list[slot] = make_int2(n, (i1 << 16) | i2);
            } else {
                min_idx[n] = i1;
                min_d[n] = (float)((double)m1 - (double)xsq[n]);
            }
        }
        __syncthreads();
    }
}

// ---------- recheck_pair: fp64 compare of two candidates, 1 wave/pixel -------
__global__ __launch_bounds__(256) void recheck_pair(
    const float* __restrict__ x, const float* __restrict__ cb,
    const int* __restrict__ cnts, const int2* __restrict__ pair_list,
    int* __restrict__ min_idx, float* __restrict__ min_d,
    const float* __restrict__ xsq)
{
    int cnt = cnts[1]; if (cnt > FULLCAP) cnt = FULLCAP;
    const int l = threadIdx.x & 63;
    const int w = blockIdx.x * 4 + (threadIdx.x >> 6);
    for (int f = w; f < cnt; f += gridDim.x * 4) {
        int2 pr = pair_list[f];
        int n = pr.x, i1 = pr.y >> 16, i2 = pr.y & 0xFFFF;
        int b = n >> 12, hw = n & 4095;
        const float* xb = x + (size_t)b * CC * HWIMG + hw;
        float4 e1 = *(const float4*)&cb[(size_t)i1 * CC + l * 4];
        float4 e2 = *(const float4*)&cb[(size_t)i2 * CC + l * 4];
        float e1a[4] = {e1.x, e1.y, e1.z, e1.w};
        float e2a[4] = {e2.x, e2.y, e2.z, e2.w};
        double s1 = 0.0, s2 = 0.0;
        #pragma unroll
        for (int j = 0; j < 4; ++j) {
            double xd = (double)xb[(size_t)(l * 4 + j) * HWIMG];
            double d1 = xd - (double)e1a[j];
            double d2 = xd - (double)e2a[j];
            s1 = fma(d1, d1, s1);
            s2 = fma(d2, d2, s2);
        }
        #pragma unroll
        for (int m = 32; m; m >>= 1) {
            s1 += __shfl_xor(s1, m, 64);
            s2 += __shfl_xor(s2, m, 64);
        }
        if (l == 0) {
            bool sec = (s2 < s1) || (s2 == s1 && i2 < i1);
            min_idx[n] = sec ? i2 : i1;
            double dw = sec ? s2 : s1;
            min_d[n] = (float)(dw - (double)xsq[n]);
        }
    }
}

// ---------- recheck_full4: fp64 exact argmin, 4 flagged pixels per block -----
__global__ __launch_bounds__(256) void recheck_full4(
    const float* __restrict__ x, const float* __restrict__ cb,
    const int* __restrict__ cnts, const int* __restrict__ full_list,
    int* __restrict__ min_idx, float* __restrict__ min_d,
    const float* __restrict__ xsq)
{
    __shared__ float  xs[4][CC];
    __shared__ double rbest[4][256];
    __shared__ int    ribst[4][256];
    int cnt = cnts[2]; if (cnt > FULL2CAP) cnt = FULL2CAP;
    int ngrp = (cnt + 3) >> 2;
    const int t = threadIdx.x;
    for (int g = blockIdx.x; g < ngrp; g += gridDim.x) {
        int npx = cnt - g * 4; if (npx > 4) npx = 4;
        for (int i = t; i < npx * 256; i += 256) {
            int p = i >> 8, c = i & 255;
            int n = full_list[g * 4 + p];
            int b = n >> 12, hw = n & 4095;
            xs[p][c] = x[(size_t)b * CC * HWIMG + (size_t)c * HWIMG + hw];
        }
        __syncthreads();
        double best[4] = {1e300, 1e300, 1e300, 1e300};
        int bi[4] = {0, 0, 0, 0};
        #pragma unroll
        for (int kk = 0; kk < 4; ++kk) {
            int k = t * 4 + kk;
            const float4* er = (const float4*)(cb + (size_t)k * CC);
            double s[4] = {0.0, 0.0, 0.0, 0.0};
            #pragma unroll 4
            for (int c4 = 0; c4 < 64; ++c4) {
                float4 e = er[c4];
                float ea[4] = {e.x, e.y, e.z, e.w};
                #pragma unroll
                for (int jj = 0; jj < 4; ++jj) {
                    #pragma unroll
                    for (int p = 0; p < 4; ++p) {
                        double d = (double)xs[p][c4 * 4 + jj] - (double)ea[jj];
                        s[p] = fma(d, d, s[p]);
                    }
                }
            }
            #pragma unroll
            for (int p = 0; p < 4; ++p)
                if (s[p] < best[p]) { best[p] = s[p]; bi[p] = k; }
        }
        #pragma unroll
        for (int p = 0; p < 4; ++p) { rbest[p][t] = best[p]; ribst[p][t] = bi[p]; }
        __syncthreads();
        for (int st = 128; st; st >>= 1) {
            if (t < st) {
                #pragma unroll
                for (int p = 0; p < 4; ++p) {
                    double ov = rbest[p][t + st]; int oi = ribst[p][t + st];
                    if (ov < rbest[p][t] || (ov == rbest[p][t] && oi < ribst[p][t])) {
                        rbest[p][t] = ov; ribst[p][t] = oi;
                    }
                }
            }
            __syncthreads();
        }
        if (t < npx) {
            int n = full_list[g * 4 + t];
            min_idx[n] = ribst[t][0];
            min_d[n] = (float)(rbest[t][0] - (double)xsq[n]);
        }
        __syncthreads();
    }
}

// ---------- out: gather quantized rows (NCHW) + fused loss partials ----------
__global__ __launch_bounds__(256) void out_kernel(
    const float* __restrict__ cb, const int* __restrict__ min_idx,
    float* __restrict__ out,
    const float* __restrict__ min_d, const float* __restrict__ xsq,
    double* __restrict__ partials)
{
    int n = blockIdx.x * 256 + threadIdx.x;
    int b = n >> 12, hw = n & 4095;
    float* ob = out + (size_t)b * CC * HWIMG + hw;
    int k = min_idx[n];
    const float* er = cb + (size_t)k * CC;
    #pragma unroll 8
    for (int c = 0; c < CC; c += 4) {
        float4 q = *(const float4*)&er[c];
        ob[(size_t)(c + 0) * HWIMG] = q.x;
        ob[(size_t)(c + 1) * HWIMG] = q.y;
        ob[(size_t)(c + 2) * HWIMG] = q.z;
        ob[(size_t)(c + 3) * HWIMG] = q.w;
    }
    __shared__ double sred[256];
    sred[threadIdx.x] = (double)min_d[n] + (double)xsq[n];
    __syncthreads();
    for (int s = 128; s; s >>= 1) {
        if (threadIdx.x < (unsigned)s) sred[threadIdx.x] += sred[threadIdx.x + s];
        __syncthreads();
    }
    if (threadIdx.x == 0) partials[blockIdx.x] = sred[0];
}

__global__ void loss_kernel(const double* __restrict__ partials, float* __restrict__ out)
{
    if (threadIdx.x == 0 && blockIdx.x == 0) {
        double s = 0.0;
        for (int i = 0; i < 512; i++) s += partials[i];
        out[33554432] = (float)(1.25 * s / 33554432.0);
    }
}

// ---------- launch -----------------------------------------------------------
extern "C" void kernel_launch(void* const* d_in, const int* in_sizes, int n_in,
                              void* d_out, int out_size, void* d_ws, size_t ws_size,
                              hipStream_t stream)
{
    const float* x  = (const float*)d_in[0];
    const float* cb = (const float*)d_in[1];
    float* out = (float*)d_out;

    // x_frag (64 MB) lives in d_out; out_kernel rewrites d_out afterwards.
    char* x_frag = (char*)d_out;

    char* ws = (char*)d_ws;
    char*   e_prep     = (char*) (ws + 0);            //   524,288 B
    float*  esq        = (float*)(ws + 524288);       //     4,096 B
    int*    min_idx    = (int*)  (ws + 528384);       //   524,288 B
    int*    cnts       = (int*)  (ws + 1052672);      //        16 B
    int*    full_list  = (int*)  (ws + 1052688);      //   131,072 B
    int2*   pair_list  = (int2*) (ws + 1183760);      //   262,144 B
    int*    full2_list = (int*)  (ws + 1445904);      //    32,768 B
    double* partials   = (double*)(ws + 1478672);     //     4,096 B
    float*  min_d      = (float*)(ws + 1482768);      //   524,288 B
    float*  xsq        = (float*)(ws + 2007056);      //   524,288 B

    prep_e        <<<KCODES, 256, 0, stream>>>(cb, e_prep, esq, cnts);
    prep_xT       <<<NPIX / 64, 256, 0, stream>>>(x, x_frag, xsq);
    dist_kernel   <<<NPIX / 128, 256, 0, stream>>>(x_frag, e_prep, esq,
                                                   min_idx, min_d, cnts, full_list);
    recheck_sweep8<<<512, 256, 0, stream>>>(x, cb, cnts, full_list,
                                            min_idx, min_d, xsq,
                                            pair_list, full2_list);
    recheck_pair  <<<512, 256, 0, stream>>>(x, cb, cnts, pair_list,
                                            min_idx, min_d, xsq);
    recheck_full4 <<<64, 256, 0, stream>>>(x, cb, cnts, full2_list,
                                           min_idx, min_d, xsq);
    out_kernel    <<<NPIX / 256, 256, 0, stream>>>(cb, min_idx, out,
                                                   min_d, xsq, partials);
    loss_kernel   <<<1, 64, 0, stream>>>(partials, out);
}

// Round 23
// 211.022 us; speedup vs baseline: 1.2188x; 1.2188x over previous
//
#include <hip/hip_runtime.h>
#include <hip/hip_fp16.h>

#define CC 256
#define HWIMG 4096
#define NPIX 131072
#define KCODES 1024
#define FULLCAP 32768
#define FULL2CAP 8192
#define KMARGIN 0.0625f   // fp16 key-space margin <=> distance margin 0.125
#define FM2 0.002f        // fp32 sweep margin (error bound ~1e-4)

typedef _Float16 half8 __attribute__((ext_vector_type(8)));
typedef short short8v __attribute__((ext_vector_type(8)));
typedef float f32x4 __attribute__((ext_vector_type(4)));
typedef unsigned short u16;
typedef unsigned int u32;

__device__ __forceinline__ void gld16(const void* g, void* l) {
    __builtin_amdgcn_global_load_lds(
        (const __attribute__((address_space(1))) void*)g,
        (__attribute__((address_space(3))) void*)l, 16, 0, 0);
}

// min-semantics sorted-triple merge with index tie-breaks
__device__ __forceinline__ void merge3(
    float& m1, int& i1, float& m2, int& i2, float& m3,
    float b1, int j1, float b2, int j2, float b3)
{
    if (b1 < m1 || (b1 == m1 && j1 < i1)) {
        float t; int ti;
        t = m1; m1 = b1; b1 = t;  ti = i1; i1 = j1; j1 = ti;
        t = m2; m2 = b2; b2 = t;  ti = i2; i2 = j2; j2 = ti;
        t = m3; m3 = b3; b3 = t;
    }
    if (b1 < m2 || (b1 == m2 && j1 < i2)) {
        m3 = fminf(m2, b2);
        m2 = b1; i2 = j1;
    } else {
        m3 = fminf(m3, b1);
    }
}

// e image: [pass 4][cpair 4][256 rows][128B]; row = code&255; 8 slots of 16B;
// slot = b*4+kg covers ch cpair*64+b*32+kg*8; phys slot = slot ^ (row & 7).

// ---------- prep_e: codebook -> fp16 pair-images + (-esq/2) + zero counters --
__global__ __launch_bounds__(256) void prep_e(const float* __restrict__ cb,
    char* __restrict__ e_prep, float* __restrict__ esq, int* __restrict__ cnts)
{
    __shared__ u16 eh[256];
    __shared__ float red[4];
    int k = blockIdx.x, c = threadIdx.x;
    float v = cb[(size_t)k * CC + c];
    eh[c] = __half_as_ushort(__float2half(v));
    float s = v * v;
    #pragma unroll
    for (int m = 32; m; m >>= 1) s += __shfl_xor(s, m, 64);
    if ((c & 63) == 0) red[c >> 6] = s;
    __syncthreads();
    if (c == 0) {
        esq[k] = -0.5f * ((red[0] + red[1]) + (red[2] + red[3]));
        if (k == 0) { cnts[0] = 0; cnts[1] = 0; cnts[2] = 0; }
    }
    if (c < 32) {
        int cpair = c >> 3, phys = c & 7;
        int pass = k >> 8, row = k & 255;
        int slot = phys ^ (row & 7);
        int cst = cpair * 64 + (slot >> 2) * 32 + (slot & 3) * 8;
        short8v w;
        #pragma unroll
        for (int j = 0; j < 8; ++j) w[j] = (short)eh[cst + j];
        *(short8v*)(e_prep + (size_t)(pass * 4 + cpair) * 32768 + row * 128 + phys * 16) = w;
    }
}

// ---------- prep_xT: x NCHW fp32 -> fp16 frag-major image (d_out) + xsq ------
__global__ __launch_bounds__(256) void prep_xT(const float* __restrict__ x,
    char* __restrict__ x_frag, float* __restrict__ xsq)
{
    __shared__ u32 pk[64 * 261];
    __shared__ float xsq_p[256];
    const int blk = blockIdx.x, t = threadIdx.x;
    const float* xb = x + (size_t)(blk >> 6) * (CC * HWIMG) + (blk & 63) * 64;
    #pragma unroll 4
    for (int p = 0; p < 16; ++p) {
        int c = p * 16 + (t >> 4);
        int px4 = (t & 15) * 4;
        float4 v = *(const float4*)&xb[(size_t)c * HWIMG + px4];
        float vv[4] = {v.x, v.y, v.z, v.w};
        #pragma unroll
        for (int i = 0; i < 4; ++i)
            pk[(px4 + i) * 261 + c] = (u32)__half_as_ushort(__float2half(vv[i]));
    }
    __syncthreads();
    {
        int px = t & 63, qr = t >> 6;
        const u32* pr = &pk[px * 261 + qr * 64];
        float s = 0.f;
        #pragma unroll 4
        for (int c = 0; c < 64; ++c) {
            float h = __half2float(__ushort_as_half((u16)pr[c]));
            s = fmaf(h, h, s);
        }
        xsq_p[t] = s;
    }
    char* obase = x_frag + (size_t)blk * 32768;
    #pragma unroll
    for (int i = 0; i < 8; ++i) {
        int gid = t + 256 * i;            // [f 4][kc 8][l 64]
        int l = gid & 63;
        int kc = (gid >> 6) & 7, f = gid >> 9;
        int px = f * 16 + (l & 15);
        int c0 = kc * 32 + (l >> 4) * 8;
        const u32* pr = &pk[px * 261 + c0];
        short8v ov;
        #pragma unroll
        for (int j = 0; j < 8; ++j) ov[j] = (short)(pr[j] & 0xFFFF);
        *(short8v*)(obase + gid * 16) = ov;
    }
    __syncthreads();
    if (t < 64)
        xsq[blk * 64 + t] = (xsq_p[t] + xsq_p[t + 64]) + (xsq_p[t + 128] + xsq_p[t + 192]);
}

// ---------- dist: x-stationary swapped-operand MFMA; branch-free top-2 -------
// (round-20 proven version: 256 px/block, 4 waves x 64 px, 16 e-tiles of 64.)
__global__ __launch_bounds__(256, 2) void dist_kernel(
    const char* __restrict__ x_frag, const char* __restrict__ e_prep,
    const float* __restrict__ esq_g,
    int* __restrict__ min_idx, float* __restrict__ min_d,
    int* __restrict__ cnts, int* __restrict__ full_list)
{
    __shared__ char smem[69632];          // 2 x 32KB e dbuf | 4KB (-esq/2)
    char* esql = smem + 65536;

    const int t = threadIdx.x;
    const int l = t & 63;
    const int wid = t >> 6;
    const int lrow = l & 15;
    const int kg   = l >> 4;
    const int ph0  = ((kg    ) ^ (lrow & 7)) * 16 + lrow * 128;
    const int ph1  = ((kg ^ 4) ^ (lrow & 7)) * 16 + lrow * 128;
    const int pxbase = blockIdx.x * 256 + wid * 64;

    half8 Xreg[4][8];
    #pragma unroll
    for (int f = 0; f < 4; ++f)
        #pragma unroll
        for (int kc = 0; kc < 8; ++kc)
            Xreg[f][kc] = *(const half8*)(x_frag +
                (size_t)(((pxbase >> 4) + f) * 8 + kc) * 1024 + l * 16);
    #pragma unroll
    for (int f = 0; f < 4; ++f)
        #pragma unroll
        for (int kc = 0; kc < 8; ++kc)
            asm volatile("" : "+v"(Xreg[f][kc]));

    gld16(esq_g + wid * 256 + l * 4, esql + wid * 1024);

#define STAGE(cur_, tc_) do {                                                  \
        const char* ee_ = e_prep + (size_t)((tc_) >> 2) * 131072               \
                          + ((tc_) & 3) * 8192 + wid * 32768;                  \
        char* bb_ = smem + (cur_) * 32768 + wid * 8192;                        \
        _Pragma("unroll")                                                      \
        for (int i_ = 0; i_ < 8; ++i_)                                         \
            gld16(ee_ + i_ * 1024 + l * 16, bb_ + i_ * 1024);                  \
    } while (0)

    STAGE(0, 0);
    STAGE(1, 1);

    float m1s[4], m2s[4]; int i1s[4];
    #pragma unroll
    for (int f = 0; f < 4; ++f) { m1s[f] = -3.4e38f; m2s[f] = -3.4e38f; i1s[f] = 0; }

    for (int tc = 0; tc < 16; ++tc) {
        const int cur = tc & 1;
        if (tc == 15) asm volatile("s_waitcnt vmcnt(0)" ::: "memory");
        else          asm volatile("s_waitcnt vmcnt(8)" ::: "memory");
        __builtin_amdgcn_s_barrier();
        __builtin_amdgcn_sched_barrier(0);

        const char* eL = smem + cur * 32768;

        f32x4 acc[4][4];
        #pragma unroll
        for (int mq = 0; mq < 4; ++mq) {
            float4 e4 = *(const float4*)(esql + (tc * 64 + mq * 16 + kg * 4) * 4);
            #pragma unroll
            for (int f = 0; f < 4; ++f)
                acc[mq][f] = (f32x4){e4.x, e4.y, e4.z, e4.w};
        }

        #pragma unroll
        for (int kc = 0; kc < 8; ++kc) {
            const int po = (kc >> 1) * 8192 + ((kc & 1) ? ph1 : ph0);
            half8 A[4];
            #pragma unroll
            for (int mq = 0; mq < 4; ++mq)
                A[mq] = *(const half8*)(eL + po + mq * 2048);
            #pragma unroll
            for (int mq = 0; mq < 4; ++mq)
                #pragma unroll
                for (int f = 0; f < 4; ++f)
                    acc[mq][f] = __builtin_amdgcn_mfma_f32_16x16x32_f16(
                        A[mq], Xreg[f][kc], acc[mq][f], 0, 0, 0);
        }

        // epilogue: branch-free in-lane top-2 over max-keys a = dot - esq/2
        #pragma unroll
        for (int mq = 0; mq < 4; ++mq) {
            const int cb0 = tc * 64 + mq * 16 + kg * 4;
            #pragma unroll
            for (int f = 0; f < 4; ++f) {
                #pragma unroll
                for (int q = 0; q < 4; ++q) {
                    float a = acc[mq][f][q];
                    float old1 = m1s[f];
                    m2s[f] = __builtin_amdgcn_fmed3f(old1, m2s[f], a);
                    bool gt = a > old1;
                    m1s[f] = fmaxf(old1, a);
                    i1s[f] = gt ? (cb0 + q) : i1s[f];
                }
            }
        }
        __builtin_amdgcn_sched_barrier(0);
        __builtin_amdgcn_s_barrier();
        if (tc < 14) STAGE(cur, tc + 2);
    }
#undef STAGE

    // final: merge the 4 kg-lanes per pixel (max-key semantics)
    #pragma unroll
    for (int f = 0; f < 4; ++f) {
        float m1 = m1s[f], m2 = m2s[f]; int i1 = i1s[f];
        #pragma unroll
        for (int msk = 16; msk <= 32; msk <<= 1) {
            float o1 = __shfl_xor(m1, msk, 64);
            int   oi = __shfl_xor(i1, msk, 64);
            float o2 = __shfl_xor(m2, msk, 64);
            if (o1 > m1 || (o1 == m1 && oi < i1)) {
                m2 = fmaxf(fmaxf(m2, o2), m1); m1 = o1; i1 = oi;
            } else {
                m2 = fmaxf(fmaxf(m2, o2), o1);
            }
        }
        if (kg == 0) {
            int n = pxbase + f * 16 + lrow;
            min_idx[n] = i1;
            min_d[n] = -2.0f * m1;       // = esq[i1] - 2*dot (for loss)
            if (m1 - m2 <= KMARGIN) {
                int slot = atomicAdd(&cnts[0], 1);
                if (slot < FULLCAP) full_list[slot] = n;
            }
        }
    }
}

// ---------- recheck_sweep8: fp32 sweep, 8 px/block, classify ----------------
__global__ __launch_bounds__(256) void recheck_sweep8(
    const float* __restrict__ x, const float* __restrict__ cb,
    int* __restrict__ cnts, const int* __restrict__ flag_list,
    int* __restrict__ min_idx, float* __restrict__ min_d,
    const float* __restrict__ xsq,
    int2* __restrict__ pair_list, int* __restrict__ full2_list)
{
    __shared__ float xs[8][CC];
    __shared__ float wm1[8][4], wm2[8][4], wm3[8][4];
    __shared__ int   wi1[8][4], wi2[8][4];
    int cnt = cnts[0]; if (cnt > FULLCAP) cnt = FULLCAP;
    int ngrp = (cnt + 7) >> 3;
    const int t = threadIdx.x;
    const int l = t & 63, wid = t >> 6;

    for (int g = blockIdx.x; g < ngrp; g += gridDim.x) {
        int npx = cnt - g * 8; if (npx > 8) npx = 8;
        for (int i = t; i < npx * 256; i += 256) {
            int p = i >> 8, c = i & 255;
            int n = flag_list[g * 8 + p];
            xs[p][c] = x[(size_t)(n >> 12) * CC * HWIMG + (size_t)c * HWIMG + (n & 4095)];
        }
        __syncthreads();

        float s[4][8];
        #pragma unroll
        for (int kk = 0; kk < 4; ++kk)
            #pragma unroll
            for (int p = 0; p < 8; ++p) s[kk][p] = 0.f;
        const float* er = cb + (size_t)t * 4 * CC;
        #pragma unroll 2
        for (int c4 = 0; c4 < 64; ++c4) {
            float4 e0 = *(const float4*)&er[c4 * 4];
            float4 e1 = *(const float4*)&er[CC + c4 * 4];
            float4 e2 = *(const float4*)&er[2 * CC + c4 * 4];
            float4 e3 = *(const float4*)&er[3 * CC + c4 * 4];
            float ea[4][4] = {{e0.x, e0.y, e0.z, e0.w}, {e1.x, e1.y, e1.z, e1.w},
                              {e2.x, e2.y, e2.z, e2.w}, {e3.x, e3.y, e3.z, e3.w}};
            #pragma unroll
            for (int p = 0; p < 8; ++p) {
                float4 xq = *(const float4*)&xs[p][c4 * 4];
                float xa[4] = {xq.x, xq.y, xq.z, xq.w};
                #pragma unroll
                for (int kk = 0; kk < 4; ++kk) {
                    float d0 = xa[0] - ea[kk][0];
                    float d1 = xa[1] - ea[kk][1];
                    float d2 = xa[2] - ea[kk][2];
                    float d3 = xa[3] - ea[kk][3];
                    s[kk][p] = fmaf(d0, d0, fmaf(d1, d1, fmaf(d2, d2, fmaf(d3, d3, s[kk][p]))));
                }
            }
        }

        #pragma unroll
        for (int p = 0; p < 8; ++p) {
            float m1 = 3.4e38f, m2 = 3.4e38f, m3 = 3.4e38f; int i1 = 0, i2 = 0;
            #pragma unroll
            for (int kk = 0; kk < 4; ++kk) {
                float d = s[kk][p]; int idx = t * 4 + kk;
                if (d < m1)      { m3 = m2; m2 = m1; i2 = i1; m1 = d; i1 = idx; }
                else if (d < m2) { m3 = m2; m2 = d; i2 = idx; }
                else if (d < m3) { m3 = d; }
            }
            #pragma unroll
            for (int msk = 1; msk <= 32; msk <<= 1) {
                float b1 = __shfl_xor(m1, msk, 64);
                float b2 = __shfl_xor(m2, msk, 64);
                float b3 = __shfl_xor(m3, msk, 64);
                int  j1 = __shfl_xor(i1, msk, 64);
                int  j2 = __shfl_xor(i2, msk, 64);
                merge3(m1, i1, m2, i2, m3, b1, j1, b2, j2, b3);
            }
            if (l == 0) {
                wm1[p][wid] = m1; wm2[p][wid] = m2; wm3[p][wid] = m3;
                wi1[p][wid] = i1; wi2[p][wid] = i2;
            }
        }
        __syncthreads();
        if (t < npx) {
            float m1 = wm1[t][0], m2 = wm2[t][0], m3 = wm3[t][0];
            int i1 = wi1[t][0], i2 = wi2[t][0];
            #pragma unroll
            for (int w = 1; w < 4; ++w)
                merge3(m1, i1, m2, i2, m3,
                       wm1[t][w], wi1[t][w], wm2[t][w], wi2[t][w], wm3[t][w]);
            int n = flag_list[g * 8 + t];
            if (m3 - m1 <= FM2) {
                int slot = atomicAdd(&cnts[2], 1);
                if (slot < FULL2CAP) full2_list[slot] = n;
            } else if (m2 - m1 <= FM2) {
                int slot = atomicAdd(&cnts[1], 1);
                if (slot < FULLCAP) pair_list[slot] = make_int2(n, (i1 << 16) | i2);
            } else {
                min_idx[n] = i1;
                min_d[n] = (float)((double)m1 - (double)xsq[n]);
            }
        }
        __syncthreads();
    }
}

// ---------- recheck_pair: fp64 compare of two candidates, 1 wave/pixel -------
__global__ __launch_bounds__(256) void recheck_pair(
    const float* __restrict__ x, const float* __restrict__ cb,
    const int* __restrict__ cnts, const int2* __restrict__ pair_list,
    int* __restrict__ min_idx, float* __restrict__ min_d,
    const float* __restrict__ xsq)
{
    int cnt = cnts[1]; if (cnt > FULLCAP) cnt = FULLCAP;
    const int l = threadIdx.x & 63;
    const int w = blockIdx.x * 4 + (threadIdx.x >> 6);
    for (int f = w; f < cnt; f += gridDim.x * 4) {
        int2 pr = pair_list[f];
        int n = pr.x, i1 = pr.y >> 16, i2 = pr.y & 0xFFFF;
        int b = n >> 12, hw = n & 4095;
        const float* xb = x + (size_t)b * CC * HWIMG + hw;
        float4 e1 = *(const float4*)&cb[(size_t)i1 * CC + l * 4];
        float4 e2 = *(const float4*)&cb[(size_t)i2 * CC + l * 4];
        float e1a[4] = {e1.x, e1.y, e1.z, e1.w};
        float e2a[4] = {e2.x, e2.y, e2.z, e2.w};
        double s1 = 0.0, s2 = 0.0;
        #pragma unroll
        for (int j = 0; j < 4; ++j) {
            double xd = (double)xb[(size_t)(l * 4 + j) * HWIMG];
            double d1 = xd - (double)e1a[j];
            double d2 = xd - (double)e2a[j];
            s1 = fma(d1, d1, s1);
            s2 = fma(d2, d2, s2);
        }
        #pragma unroll
        for (int m = 32; m; m >>= 1) {
            s1 += __shfl_xor(s1, m, 64);
            s2 += __shfl_xor(s2, m, 64);
        }
        if (l == 0) {
            bool sec = (s2 < s1) || (s2 == s1 && i2 < i1);
            min_idx[n] = sec ? i2 : i1;
            double dw = sec ? s2 : s1;
            min_d[n] = (float)(dw - (double)xsq[n]);
        }
    }
}

// ---------- recheck_full4: fp64 exact argmin, 4 flagged pixels per block -----
__global__ __launch_bounds__(256) void recheck_full4(
    const float* __restrict__ x, const float* __restrict__ cb,
    const int* __restrict__ cnts, const int* __restrict__ full_list,
    int* __restrict__ min_idx, float* __restrict__ min_d,
    const float* __restrict__ xsq)
{
    __shared__ float  xs[4][CC];
    __shared__ double rbest[4][256];
    __shared__ int    ribst[4][256];
    int cnt = cnts[2]; if (cnt > FULL2CAP) cnt = FULL2CAP;
    int ngrp = (cnt + 3) >> 2;
    const int t = threadIdx.x;
    for (int g = blockIdx.x; g < ngrp; g += gridDim.x) {
        int npx = cnt - g * 4; if (npx > 4) npx = 4;
        for (int i = t; i < npx * 256; i += 256) {
            int p = i >> 8, c = i & 255;
            int n = full_list[g * 4 + p];
            int b = n >> 12, hw = n & 4095;
            xs[p][c] = x[(size_t)b * CC * HWIMG + (size_t)c * HWIMG + hw];
        }
        __syncthreads();
        double best[4] = {1e300, 1e300, 1e300, 1e300};
        int bi[4] = {0, 0, 0, 0};
        #pragma unroll
        for (int kk = 0; kk < 4; ++kk) {
            int k = t * 4 + kk;
            const float4* er = (const float4*)(cb + (size_t)k * CC);
            double s[4] = {0.0, 0.0, 0.0, 0.0};
            #pragma unroll 4
            for (int c4 = 0; c4 < 64; ++c4) {
                float4 e = er[c4];
                float ea[4] = {e.x, e.y, e.z, e.w};
                #pragma unroll
                for (int jj = 0; jj < 4; ++jj) {
                    #pragma unroll
                    for (int p = 0; p < 4; ++p) {
                        double d = (double)xs[p][c4 * 4 + jj] - (double)ea[jj];
                        s[p] = fma(d, d, s[p]);
                    }
                }
            }
            #pragma unroll
            for (int p = 0; p < 4; ++p)
                if (s[p] < best[p]) { best[p] = s[p]; bi[p] = k; }
        }
        #pragma unroll
        for (int p = 0; p < 4; ++p) { rbest[p][t] = best[p]; ribst[p][t] = bi[p]; }
        __syncthreads();
        for (int st = 128; st; st >>= 1) {
            if (t < st) {
                #pragma unroll
                for (int p = 0; p < 4; ++p) {
                    double ov = rbest[p][t + st]; int oi = ribst[p][t + st];
                    if (ov < rbest[p][t] || (ov == rbest[p][t] && oi < ribst[p][t])) {
                        rbest[p][t] = ov; ribst[p][t] = oi;
                    }
                }
            }
            __syncthreads();
        }
        if (t < npx) {
            int n = full_list[g * 4 + t];
            min_idx[n] = ribst[t][0];
            min_d[n] = (float)(rbest[t][0] - (double)xsq[n]);
        }
        __syncthreads();
    }
}

// ---------- out: gather quantized rows (NCHW) + fused loss partials ----------
__global__ __launch_bounds__(256) void out_kernel(
    const float* __restrict__ cb, const int* __restrict__ min_idx,
    float* __restrict__ out,
    const float* __restrict__ min_d, const float* __restrict__ xsq,
    double* __restrict__ partials)
{
    int n = blockIdx.x * 256 + threadIdx.x;
    int b = n >> 12, hw = n & 4095;
    float* ob = out + (size_t)b * CC * HWIMG + hw;
    int k = min_idx[n];
    const float* er = cb + (size_t)k * CC;
    #pragma unroll 8
    for (int c = 0; c < CC; c += 4) {
        float4 q = *(const float4*)&er[c];
        ob[(size_t)(c + 0) * HWIMG] = q.x;
        ob[(size_t)(c + 1) * HWIMG] = q.y;
        ob[(size_t)(c + 2) * HWIMG] = q.z;
        ob[(size_t)(c + 3) * HWIMG] = q.w;
    }
    __shared__ double sred[256];
    sred[threadIdx.x] = (double)min_d[n] + (double)xsq[n];
    __syncthreads();
    for (int s = 128; s; s >>= 1) {
        if (threadIdx.x < (unsigned)s) sred[threadIdx.x] += sred[threadIdx.x + s];
        __syncthreads();
    }
    if (threadIdx.x == 0) partials[blockIdx.x] = sred[0];
}

__global__ void loss_kernel(const double* __restrict__ partials, float* __restrict__ out)
{
    if (threadIdx.x == 0 && blockIdx.x == 0) {
        double s = 0.0;
        for (int i = 0; i < 512; i++) s += partials[i];
        out[33554432] = (float)(1.25 * s / 33554432.0);
    }
}

// ---------- launch -----------------------------------------------------------
extern "C" void kernel_launch(void* const* d_in, const int* in_sizes, int n_in,
                              void* d_out, int out_size, void* d_ws, size_t ws_size,
                              hipStream_t stream)
{
    const float* x  = (const float*)d_in[0];
    const float* cb = (const float*)d_in[1];
    float* out = (float*)d_out;

    // x_frag (64 MB) lives in d_out; out_kernel rewrites d_out afterwards.
    char* x_frag = (char*)d_out;

    char* ws = (char*)d_ws;
    char*   e_prep     = (char*) (ws + 0);            //   524,288 B
    float*  esq        = (float*)(ws + 524288);       //     4,096 B
    int*    min_idx    = (int*)  (ws + 528384);       //   524,288 B
    int*    cnts       = (int*)  (ws + 1052672);      //        16 B
    int*    full_list  = (int*)  (ws + 1052688);      //   131,072 B
    int2*   pair_list  = (int2*) (ws + 1183760);      //   262,144 B
    int*    full2_list = (int*)  (ws + 1445904);      //    32,768 B
    double* partials   = (double*)(ws + 1478672);     //     4,096 B
    float*  min_d      = (float*)(ws + 1482768);      //   524,288 B
    float*  xsq        = (float*)(ws + 2007056);      //   524,288 B

    prep_e        <<<KCODES, 256, 0, stream>>>(cb, e_prep, esq, cnts);
    prep_xT       <<<NPIX / 64, 256, 0, stream>>>(x, x_frag, xsq);
    dist_kernel   <<<512, 256, 0, stream>>>(x_frag, e_prep, esq,
                                            min_idx, min_d, cnts, full_list);
    recheck_sweep8<<<512, 256, 0, stream>>>(x, cb, cnts, full_list,
                                            min_idx, min_d, xsq,
                                            pair_list, full2_list);
    recheck_pair  <<<512, 256, 0, stream>>>(x, cb, cnts, pair_list,
                                            min_idx, min_d, xsq);
    recheck_full4 <<<64, 256, 0, stream>>>(x, cb, cnts, full2_list,
                                           min_idx, min_d, xsq);
    out_kernel    <<<NPIX / 256, 256, 0, stream>>>(cb, min_idx, out,
                                                   min_d, xsq, partials);
    loss_kernel   <<<1, 64, 0, stream>>>(partials, out);
}